// Round 9
// baseline (626.603 us; speedup 1.0000x reference)
//
#include <hip/hip_runtime.h>

#define NB 8
#define NN 128
#define ND 64
#define NE 3
#define NH 256
#define NOUT 64

typedef short bf16x8_t __attribute__((ext_vector_type(8)));
typedef float f32x4_t __attribute__((ext_vector_type(4)));
typedef unsigned short ushort_t;

static __device__ __forceinline__ unsigned short f2bf(float f) {
    unsigned u = __float_as_uint(f);
    u += 0x7FFFu + ((u >> 16) & 1u);
    return (unsigned short)(u >> 16);
}
static __device__ __forceinline__ unsigned pk2bf(float a, float b) {
    return (unsigned)f2bf(a) | ((unsigned)f2bf(b) << 16);
}
static __device__ __forceinline__ float bflo(unsigned u) { return __uint_as_float(u << 16); }
static __device__ __forceinline__ float bfhi(unsigned u) { return __uint_as_float(u & 0xffff0000u); }

// A-fragment gen: relu(P + Q) in f32, round to bf16, pack to bf16x8
static __device__ __forceinline__ bf16x8_t a_gen(uint4 pv, uint4 qv) {
    union { uint4 u; bf16x8_t v; } r;
    const float f0 = fmaxf(bflo(pv.x) + bflo(qv.x), 0.f);
    const float f1 = fmaxf(bfhi(pv.x) + bfhi(qv.x), 0.f);
    const float f2 = fmaxf(bflo(pv.y) + bflo(qv.y), 0.f);
    const float f3 = fmaxf(bfhi(pv.y) + bfhi(qv.y), 0.f);
    const float f4 = fmaxf(bflo(pv.z) + bflo(qv.z), 0.f);
    const float f5 = fmaxf(bfhi(pv.z) + bfhi(qv.z), 0.f);
    const float f6 = fmaxf(bflo(pv.w) + bflo(qv.w), 0.f);
    const float f7 = fmaxf(bfhi(pv.w) + bfhi(qv.w), 0.f);
    r.u.x = pk2bf(f0, f1); r.u.y = pk2bf(f2, f3);
    r.u.z = pk2bf(f4, f5); r.u.w = pk2bf(f6, f7);
    return r.v;
}

// ============ Kernel 1: We2t transpose (0..191) + P/Q (192..383) + edge pack (384..1407) ============
#define IT 16
__global__ __launch_bounds__(256) void prep_kernel(
    const float* __restrict__ We2, const float* __restrict__ ns,
    const float* __restrict__ We1, const float* __restrict__ be1,
    const float* __restrict__ edges,
    ushort_t* __restrict__ We2t,
    ushort_t* __restrict__ P, ushort_t* __restrict__ Q,
    ushort_t* __restrict__ list_ws, int4* __restrict__ cnts_ws)
{
    __shared__ float tile[32][33];
    __shared__ float ns_lds[IT][ND];
    __shared__ unsigned long long wm[2][NE];
    const int t = threadIdx.x;
    const int blk = blockIdx.x;

    if (blk < 192) {            // ---- We2t[e][n][k] = bf16(We2[e][k][n]) ----
        const int tx = t & 31, ty = t >> 5;
        const int e = blk >> 6, kt = (blk >> 3) & 7, nt = blk & 7;
        const float* src = We2 + ((size_t)e * NH + kt * 32) * NH + nt * 32;
#pragma unroll
        for (int s = 0; s < 4; s++) { const int k = ty + 8 * s; tile[k][tx] = src[(size_t)k * NH + tx]; }
        __syncthreads();
        ushort_t* dst = We2t + ((size_t)e * NH + nt * 32) * NH + kt * 32;
#pragma unroll
        for (int s = 0; s < 4; s++) { const int n = ty + 8 * s; dst[(size_t)n * NH + tx] = f2bf(tile[tx][n]); }
        return;
    }
    if (blk < 384) {            // ---- P/Q precompute -> bf16 ----
        const int blk2 = blk - 192;
        const int itile = blk2 & 7;
        const int e = (blk2 >> 3) % NE;
        const int b = blk2 / 24;
        const int i0 = itile * IT;
        for (int x = t; x < IT * ND; x += 256)
            ns_lds[x / ND][x % ND] = ns[(size_t)(b * NN + i0 + x / ND) * ND + (x % ND)];
        __syncthreads();
        const int h = t;
        float accP[IT], accQ[IT];
        const float bias = be1[e * NH + h];
#pragma unroll
        for (int m = 0; m < IT; m++) { accP[m] = 0.f; accQ[m] = bias; }
        const float* W1 = We1 + (size_t)e * 2 * ND * NH + h;
        for (int d = 0; d < ND; d++) {
            const float w1 = W1[(size_t)d * NH];
            const float w2 = W1[(size_t)(ND + d) * NH];
#pragma unroll
            for (int m = 0; m < IT; m++) {
                accP[m] = fmaf(ns_lds[m][d], w1, accP[m]);
                accQ[m] = fmaf(ns_lds[m][d], w2, accQ[m]);
            }
        }
#pragma unroll
        for (int m = 0; m < IT; m++) {
            const size_t idx = ((size_t)((b * NE + e) * NN) + i0 + m) * NH + h;
            P[idx] = f2bf(accP[m]);
            Q[idx] = f2bf(accQ[m]);
        }
        return;
    }
    // ---- edge pack: per (b,j): bucketed source lists by edge type ----
    {
        const int pb = blk - 384;
        const int b = pb >> 7, j = pb & 127;
        const int lane = t & 63, wave = t >> 6;
        int ecls = -1;
        if (t < 128) {
            const float4 ev = *(const float4*)(edges + ((size_t)(b * NN + t) * NN + j) * 4);
            ecls = ev.y > 0.5f ? 0 : (ev.z > 0.5f ? 1 : (ev.w > 0.5f ? 2 : -1));
#pragma unroll
            for (int ee = 0; ee < NE; ee++) {
                unsigned long long m = __ballot(ecls == ee);
                if (lane == 0) wm[wave][ee] = m;
            }
        }
        __syncthreads();
        const int c0 = __popcll(wm[0][0]) + __popcll(wm[1][0]);
        const int c1 = __popcll(wm[0][1]) + __popcll(wm[1][1]);
        const int c2 = __popcll(wm[0][2]) + __popcll(wm[1][2]);
        if (t < 128 && ecls >= 0) {
            const unsigned long long lower = (1ull << lane) - 1ull;
            int pos = __popcll(wm[wave][ecls] & lower);
            if (wave == 1) pos += __popcll(wm[0][ecls]);
            pos += (ecls > 0 ? c0 : 0) + (ecls > 1 ? c1 : 0);
            list_ws[(size_t)pb * NN + pos] = (ushort_t)t;
        }
        if (t == 0) { int4 cc; cc.x = c0; cc.y = c1; cc.z = c2; cc.w = 0; cnts_ws[pb] = cc; }
    }
}

// ============ Kernel 2: batched masked GEMM, frag-aligned j-groups, no hot barriers ============
static __device__ __forceinline__ void epilogue_frag(
    const f32x4_t* acc, int f, int ce, const float* bb, int lane, float* aggrow)
{
#pragma unroll
    for (int nf = 0; nf < 8; nf++) {
        float s = 0.f;
#pragma unroll
        for (int r4 = 0; r4 < 4; r4++) {
            const int pos = f * 16 + ((lane >> 4) << 2) + r4;
            if (pos < ce) s += fmaxf(acc[nf][r4] + bb[nf], 0.f);
        }
        s += __shfl_xor(s, 16, 64);
        s += __shfl_xor(s, 32, 64);
        if (lane < 16) aggrow[nf * 16 + lane] += s;
    }
}

__global__ __launch_bounds__(256) void gemm_kernel(
    const ushort_t* __restrict__ Pbf,
    const ushort_t* __restrict__ Qbf,
    const ushort_t* __restrict__ We2t,
    const float* __restrict__ be2,
    const ushort_t* __restrict__ list_ws,
    const int4* __restrict__ cnts_ws,
    float* __restrict__ aggr3)
{
    const int blk = blockIdx.x;           // 768 = b(8) x e(3) x jg(16) x nh(2)
    const int b = blk / 96;
    const int r = blk % 96;
    const int e = r >> 5;
    const int jg = (r >> 1) & 15;
    const int nh = r & 1;
    const int tid = threadIdx.x;
    const int lane = tid & 63;
    const int wave = tid >> 6;

    __shared__ ushort_t listL[8][NN];
    __shared__ float aggrL[8][128];
    __shared__ int ceL[8];

    // stage this block's 8 j-lists (for edge type e) + zero the output accumulator
    {
        const int jl = tid >> 5, q = tid & 31;
        const int j = jg * 8 + jl;
        const int4 cc = cnts_ws[b * NN + j];
        const int ce = e == 0 ? cc.x : (e == 1 ? cc.y : cc.z);
        const int start = (e > 0 ? cc.x : 0) + (e > 1 ? cc.y : 0);
        if (q == 0) ceL[jl] = ce;
        for (int idx = q; idx < ce; idx += 32)
            listL[jl][idx] = list_ws[(size_t)(b * NN + j) * NN + start + idx];
        for (int x = tid; x < 1024; x += 256) aggrL[x >> 7][x & 127] = 0.f;
    }
    __syncthreads();

    float bb[8];
#pragma unroll
    for (int nf = 0; nf < 8; nf++)
        bb[nf] = be2[e * NH + nh * 128 + nf * 16 + (lane & 15)];

    const ushort_t* Pb = Pbf + (size_t)(b * NE + e) * NN * NH;
    const ushort_t* Bt = We2t + (size_t)e * NH * NH + (size_t)(nh * 128) * NH;

    // each wave owns 2 j's; fully independent (no barriers) until the final store
    for (int jl = wave * 2; jl < wave * 2 + 2; jl++) {
        const int ce = ceL[jl];
        if (ce == 0) continue;
        const int j = jg * 8 + jl;
        const ushort_t* Qj = Qbf + (size_t)((b * NE + e) * NN + j) * NH;
        const int F = (ce + 15) >> 4;
        for (int f0 = 0; f0 < F; f0 += 2) {
            const int nfr = (F - f0) < 2 ? (F - f0) : 2;
            int p0 = f0 * 16 + (lane & 15);          p0 = p0 < ce ? p0 : ce - 1;
            int p1 = (f0 + 1) * 16 + (lane & 15);    p1 = p1 < ce ? p1 : ce - 1;
            const ushort_t* P0 = Pb + (size_t)listL[jl][p0] * NH;
            const ushort_t* P1 = Pb + (size_t)listL[jl][p1] * NH;

            f32x4_t acc0[8], acc1[8];
            const f32x4_t z4 = {0.f, 0.f, 0.f, 0.f};
#pragma unroll
            for (int nf = 0; nf < 8; nf++) { acc0[nf] = z4; acc1[nf] = z4; }

#pragma unroll
            for (int kk = 0; kk < 8; kk++) {
                const int ko = kk * 32 + (lane >> 4) * 8;
                const uint4 qv = *(const uint4*)(Qj + ko);
                const bf16x8_t af0 = a_gen(*(const uint4*)(P0 + ko), qv);
                bf16x8_t af1;
                if (nfr == 2) af1 = a_gen(*(const uint4*)(P1 + ko), qv);
#pragma unroll
                for (int nf = 0; nf < 8; nf++) {
                    const bf16x8_t bfr = *(const bf16x8_t*)(Bt + (size_t)(nf * 16 + (lane & 15)) * NH + ko);
                    acc0[nf] = __builtin_amdgcn_mfma_f32_16x16x32_bf16(af0, bfr, acc0[nf], 0, 0, 0);
                    if (nfr == 2)
                        acc1[nf] = __builtin_amdgcn_mfma_f32_16x16x32_bf16(af1, bfr, acc1[nf], 0, 0, 0);
                }
            }
            epilogue_frag(acc0, f0, ce, bb, lane, aggrL[jl]);
            if (nfr == 2) epilogue_frag(acc1, f0 + 1, ce, bb, lane, aggrL[jl]);
        }
    }
    __syncthreads();
    // store per-e partial aggr (unique writer per (b,e,j,col) -> deterministic, no atomics)
    for (int x = tid; x < 1024; x += 256) {
        const int jl = x >> 7, col = x & 127;
        aggr3[(size_t)((b * NE + e) * NN + jg * 8 + jl) * NH + nh * 128 + col] = aggrL[jl][col];
    }
}

// ============ Kernel 3: decoder, 8 j's per block (weight reuse x8) ============
__global__ __launch_bounds__(256) void dec_kernel(
    const float* __restrict__ ns,
    const float* __restrict__ aggr3,
    const float* __restrict__ Wd1, const float* __restrict__ bd1,
    const float* __restrict__ Wd2, const float* __restrict__ bd2,
    float* __restrict__ out)
{
    const int b = blockIdx.x >> 4;
    const int jg = blockIdx.x & 15;
    const int tid = threadIdx.x;
    __shared__ __align__(16) float xs[8][320];
    __shared__ __align__(16) float o1s[8][NH];

    // stage x = [ns(64) | sum_e aggr3(256)] for 8 j's
    for (int x = tid; x < 8 * 320; x += 256) {
        const int jj = x / 320, k = x % 320;
        const int j = jg * 8 + jj;
        float v;
        if (k < ND) v = ns[(size_t)(b * NN + j) * ND + k];
        else {
            const int c = k - ND;
            v = aggr3[(size_t)((b * NE + 0) * NN + j) * NH + c]
              + aggr3[(size_t)((b * NE + 1) * NN + j) * NH + c]
              + aggr3[(size_t)((b * NE + 2) * NN + j) * NH + c];
        }
        xs[jj][k] = v;
    }
    __syncthreads();
    // layer 1: thread owns col n; 8 j's share each weight load
    {
        const int n = tid;
        float acc[8];
        const float b1 = bd1[n];
#pragma unroll
        for (int jj = 0; jj < 8; jj++) acc[jj] = b1;
        for (int k4 = 0; k4 < 80; k4++) {
            const float w0 = Wd1[(size_t)(k4 * 4 + 0) * NH + n];
            const float w1 = Wd1[(size_t)(k4 * 4 + 1) * NH + n];
            const float w2 = Wd1[(size_t)(k4 * 4 + 2) * NH + n];
            const float w3 = Wd1[(size_t)(k4 * 4 + 3) * NH + n];
#pragma unroll
            for (int jj = 0; jj < 8; jj++) {
                const float4 xv = *(const float4*)(&xs[jj][k4 * 4]);
                acc[jj] = fmaf(xv.x, w0, fmaf(xv.y, w1, fmaf(xv.z, w2, fmaf(xv.w, w3, acc[jj]))));
            }
        }
#pragma unroll
        for (int jj = 0; jj < 8; jj++) o1s[jj][n] = fmaxf(acc[jj], 0.f);
    }
    __syncthreads();
    // layer 2: thread = (jj, 2 cols)
    {
        const int jj = tid >> 5, cp = tid & 31;
        const int n0 = cp * 2;
        float a0 = bd2[n0], a1 = bd2[n0 + 1];
        for (int h4 = 0; h4 < 64; h4++) {
            const float4 ov = *(const float4*)(&o1s[jj][h4 * 4]);
            a0 = fmaf(ov.x, Wd2[(size_t)(h4 * 4 + 0) * NOUT + n0], a0);
            a1 = fmaf(ov.x, Wd2[(size_t)(h4 * 4 + 0) * NOUT + n0 + 1], a1);
            a0 = fmaf(ov.y, Wd2[(size_t)(h4 * 4 + 1) * NOUT + n0], a0);
            a1 = fmaf(ov.y, Wd2[(size_t)(h4 * 4 + 1) * NOUT + n0 + 1], a1);
            a0 = fmaf(ov.z, Wd2[(size_t)(h4 * 4 + 2) * NOUT + n0], a0);
            a1 = fmaf(ov.z, Wd2[(size_t)(h4 * 4 + 2) * NOUT + n0 + 1], a1);
            a0 = fmaf(ov.w, Wd2[(size_t)(h4 * 4 + 3) * NOUT + n0], a0);
            a1 = fmaf(ov.w, Wd2[(size_t)(h4 * 4 + 3) * NOUT + n0 + 1], a1);
        }
        const int j = jg * 8 + jj;
        out[(size_t)(b * NN + j) * NOUT + n0] = fmaxf(a0, 0.f);
        out[(size_t)(b * NN + j) * NOUT + n0 + 1] = fmaxf(a1, 0.f);
    }
}

extern "C" void kernel_launch(void* const* d_in, const int* in_sizes, int n_in,
                              void* d_out, int out_size, void* d_ws, size_t ws_size,
                              hipStream_t stream)
{
    const float* ns    = (const float*)d_in[0];
    const float* edges = (const float*)d_in[1];
    const float* We1   = (const float*)d_in[2];
    const float* be1   = (const float*)d_in[3];
    const float* We2   = (const float*)d_in[4];
    const float* be2   = (const float*)d_in[5];
    const float* Wd1   = (const float*)d_in[6];
    const float* bd1   = (const float*)d_in[7];
    const float* Wd2   = (const float*)d_in[8];
    const float* bd2   = (const float*)d_in[9];
    float* outp = (float*)d_out;

    // ws layout (~6.6 MB)
    ushort_t* Pbf  = (ushort_t*)d_ws;                       // 786432
    ushort_t* Qbf  = Pbf + (size_t)NB * NE * NN * NH;       // 786432
    ushort_t* We2t = Qbf + (size_t)NB * NE * NN * NH;       // 196608
    ushort_t* list_ws = We2t + (size_t)NE * NH * NH;        // 131072
    int4* cnts_ws = (int4*)(list_ws + (size_t)NB * NN * NN);// 1024 int4
    float* aggr3 = (float*)(cnts_ws + NB * NN);             // 786432 f32

    hipLaunchKernelGGL(prep_kernel, dim3(1408), dim3(256), 0, stream,
                       We2, ns, We1, be1, edges, We2t, Pbf, Qbf, list_ws, cnts_ws);
    hipLaunchKernelGGL(gemm_kernel, dim3(768), dim3(256), 0, stream,
                       Pbf, Qbf, We2t, be2, list_ws, cnts_ws, aggr3);
    hipLaunchKernelGGL(dec_kernel, dim3(NB * 16), dim3(256), 0, stream,
                       ns, aggr3, Wd1, bd1, Wd2, bd2, outp);
}

// Round 11
// 155.985 us; speedup vs baseline: 4.0171x; 4.0171x over previous
//
#include <hip/hip_runtime.h>

#define NB 8
#define NN 128
#define ND 64
#define NE 3
#define NH 256
#define NOUT 64

typedef short bf16x8_t __attribute__((ext_vector_type(8)));
typedef float f32x4_t __attribute__((ext_vector_type(4)));
typedef unsigned short ushort_t;

static __device__ __forceinline__ unsigned short f2bf(float f) {
    unsigned u = __float_as_uint(f);
    u += 0x7FFFu + ((u >> 16) & 1u);
    return (unsigned short)(u >> 16);
}
static __device__ __forceinline__ unsigned pk2bf(float a, float b) {
    return (unsigned)f2bf(a) | ((unsigned)f2bf(b) << 16);
}
static __device__ __forceinline__ float bflo(unsigned u) { return __uint_as_float(u << 16); }
static __device__ __forceinline__ float bfhi(unsigned u) { return __uint_as_float(u & 0xffff0000u); }

// A-fragment gen: relu(P + Q) in f32, round to bf16, pack to bf16x8
static __device__ __forceinline__ bf16x8_t a_gen(uint4 pv, uint4 qv) {
    union { uint4 u; bf16x8_t v; } r;
    const float f0 = fmaxf(bflo(pv.x) + bflo(qv.x), 0.f);
    const float f1 = fmaxf(bfhi(pv.x) + bfhi(qv.x), 0.f);
    const float f2 = fmaxf(bflo(pv.y) + bflo(qv.y), 0.f);
    const float f3 = fmaxf(bfhi(pv.y) + bfhi(qv.y), 0.f);
    const float f4 = fmaxf(bflo(pv.z) + bflo(qv.z), 0.f);
    const float f5 = fmaxf(bfhi(pv.z) + bfhi(qv.z), 0.f);
    const float f6 = fmaxf(bflo(pv.w) + bflo(qv.w), 0.f);
    const float f7 = fmaxf(bfhi(pv.w) + bfhi(qv.w), 0.f);
    r.u.x = pk2bf(f0, f1); r.u.y = pk2bf(f2, f3);
    r.u.z = pk2bf(f4, f5); r.u.w = pk2bf(f6, f7);
    return r.v;
}

// ============ Kernel 1: We2t transpose (0..191) + P/Q (192..383) + edge pack (384..1407) ============
#define IT 16
__global__ __launch_bounds__(256) void prep_kernel(
    const float* __restrict__ We2, const float* __restrict__ ns,
    const float* __restrict__ We1, const float* __restrict__ be1,
    const float* __restrict__ edges,
    ushort_t* __restrict__ We2t,
    ushort_t* __restrict__ P, ushort_t* __restrict__ Q,
    ushort_t* __restrict__ list_ws, int4* __restrict__ cnts_ws)
{
    __shared__ float tile[32][33];
    __shared__ float ns_lds[IT][ND];
    __shared__ unsigned long long wm[2][NE];
    const int t = threadIdx.x;
    const int blk = blockIdx.x;

    if (blk < 192) {            // ---- We2t[e][n][k] = bf16(We2[e][k][n]) ----
        const int tx = t & 31, ty = t >> 5;
        const int e = blk >> 6, kt = (blk >> 3) & 7, nt = blk & 7;
        const float* src = We2 + ((size_t)e * NH + kt * 32) * NH + nt * 32;
#pragma unroll
        for (int s = 0; s < 4; s++) { const int k = ty + 8 * s; tile[k][tx] = src[(size_t)k * NH + tx]; }
        __syncthreads();
        ushort_t* dst = We2t + ((size_t)e * NH + nt * 32) * NH + kt * 32;
#pragma unroll
        for (int s = 0; s < 4; s++) { const int n = ty + 8 * s; dst[(size_t)n * NH + tx] = f2bf(tile[tx][n]); }
        return;
    }
    if (blk < 384) {            // ---- P/Q precompute -> bf16 ----
        const int blk2 = blk - 192;
        const int itile = blk2 & 7;
        const int e = (blk2 >> 3) % NE;
        const int b = blk2 / 24;
        const int i0 = itile * IT;
        for (int x = t; x < IT * ND; x += 256)
            ns_lds[x / ND][x % ND] = ns[(size_t)(b * NN + i0 + x / ND) * ND + (x % ND)];
        __syncthreads();
        const int h = t;
        float accP[IT], accQ[IT];
        const float bias = be1[e * NH + h];
#pragma unroll
        for (int m = 0; m < IT; m++) { accP[m] = 0.f; accQ[m] = bias; }
        const float* W1 = We1 + (size_t)e * 2 * ND * NH + h;
        for (int d = 0; d < ND; d++) {
            const float w1 = W1[(size_t)d * NH];
            const float w2 = W1[(size_t)(ND + d) * NH];
#pragma unroll
            for (int m = 0; m < IT; m++) {
                accP[m] = fmaf(ns_lds[m][d], w1, accP[m]);
                accQ[m] = fmaf(ns_lds[m][d], w2, accQ[m]);
            }
        }
#pragma unroll
        for (int m = 0; m < IT; m++) {
            const size_t idx = ((size_t)((b * NE + e) * NN) + i0 + m) * NH + h;
            P[idx] = f2bf(accP[m]);
            Q[idx] = f2bf(accQ[m]);
        }
        return;
    }
    // ---- edge pack: per (b,j): bucketed source lists by edge type ----
    {
        const int pb = blk - 384;
        const int b = pb >> 7, j = pb & 127;
        const int lane = t & 63, wave = t >> 6;
        int ecls = -1;
        if (t < 128) {
            const float4 ev = *(const float4*)(edges + ((size_t)(b * NN + t) * NN + j) * 4);
            ecls = ev.y > 0.5f ? 0 : (ev.z > 0.5f ? 1 : (ev.w > 0.5f ? 2 : -1));
#pragma unroll
            for (int ee = 0; ee < NE; ee++) {
                unsigned long long m = __ballot(ecls == ee);
                if (lane == 0) wm[wave][ee] = m;
            }
        }
        __syncthreads();
        const int c0 = __popcll(wm[0][0]) + __popcll(wm[1][0]);
        const int c1 = __popcll(wm[0][1]) + __popcll(wm[1][1]);
        const int c2 = __popcll(wm[0][2]) + __popcll(wm[1][2]);
        if (t < 128 && ecls >= 0) {
            const unsigned long long lower = (1ull << lane) - 1ull;
            int pos = __popcll(wm[wave][ecls] & lower);
            if (wave == 1) pos += __popcll(wm[0][ecls]);
            pos += (ecls > 0 ? c0 : 0) + (ecls > 1 ? c1 : 0);
            list_ws[(size_t)pb * NN + pos] = (ushort_t)t;
        }
        if (t == 0) { int4 cc; cc.x = c0; cc.y = c1; cc.z = c2; cc.w = 0; cnts_ws[pb] = cc; }
    }
}

// ============ Kernel 2: barrier-free masked GEMM; wave = (2 j's) x 64-col quarter ============
__global__ __launch_bounds__(256) void gemm_kernel(
    const ushort_t* __restrict__ Pbf,
    const ushort_t* __restrict__ Qbf,
    const ushort_t* __restrict__ We2t,
    const float* __restrict__ be2,
    const ushort_t* __restrict__ list_ws,
    const int4* __restrict__ cnts_ws,
    float* __restrict__ aggr3)
{
    // grid: 1536 = b(8) x e(3) x jg(16) x q(4)
    const int blk = blockIdx.x;
    const int q  = blk & 3;
    const int jg = (blk >> 2) & 15;
    const int e  = (blk >> 6) % 3;
    const int b  = blk / 192;
    const int tid = threadIdx.x;
    const int lane = tid & 63;
    const int wave = tid >> 6;

    const ushort_t* Pb = Pbf + (size_t)(b * NE + e) * NN * NH;
    const ushort_t* Bt = We2t + (size_t)e * NH * NH + (size_t)(q * 64) * NH;

    float bb[4];
#pragma unroll
    for (int nf = 0; nf < 4; nf++)
        bb[nf] = be2[e * NH + q * 64 + nf * 16 + (lane & 15)];

    for (int jj = 0; jj < 2; jj++) {
        const int j = jg * 8 + wave * 2 + jj;
        const int4 cc = cnts_ws[b * NN + j];
        const int ce = e == 0 ? cc.x : (e == 1 ? cc.y : cc.z);
        const int start = (e > 0 ? cc.x : 0) + (e > 1 ? cc.y : 0);
        const ushort_t* Qj = Qbf + (size_t)((b * NE + e) * NN + j) * NH;
        const ushort_t* Lj = list_ws + (size_t)(b * NN + j) * NN + start;

        float rsum[4] = {0.f, 0.f, 0.f, 0.f};
        if (ce > 0) {
            const int F = (ce + 15) >> 4;
            for (int f0 = 0; f0 < F; f0 += 2) {
                const bool two = (f0 + 1) < F;
                int p0 = f0 * 16 + (lane & 15);        p0 = p0 < ce ? p0 : ce - 1;
                int p1 = (f0 + 1) * 16 + (lane & 15);  p1 = p1 < ce ? p1 : ce - 1;
                const ushort_t* P0 = Pb + (size_t)Lj[p0] * NH;
                const ushort_t* P1 = Pb + (size_t)Lj[p1] * NH;

                f32x4_t acc0[4], acc1[4];
                const f32x4_t z4 = {0.f, 0.f, 0.f, 0.f};
#pragma unroll
                for (int nf = 0; nf < 4; nf++) { acc0[nf] = z4; acc1[nf] = z4; }

#pragma unroll 2
                for (int kk = 0; kk < 8; kk++) {
                    const int ko = kk * 32 + (lane >> 4) * 8;
                    const uint4 qv = *(const uint4*)(Qj + ko);
                    const bf16x8_t af0 = a_gen(*(const uint4*)(P0 + ko), qv);
                    bf16x8_t af1 = af0;
                    if (two) af1 = a_gen(*(const uint4*)(P1 + ko), qv);
#pragma unroll
                    for (int nf = 0; nf < 4; nf++) {
                        const bf16x8_t bfr = *(const bf16x8_t*)(Bt + (size_t)(nf * 16 + (lane & 15)) * NH + ko);
                        acc0[nf] = __builtin_amdgcn_mfma_f32_16x16x32_bf16(af0, bfr, acc0[nf], 0, 0, 0);
                        if (two)
                            acc1[nf] = __builtin_amdgcn_mfma_f32_16x16x32_bf16(af1, bfr, acc1[nf], 0, 0, 0);
                    }
                }
                // epilogue: bias+relu+row-mask, cross-lane col reduce
#pragma unroll
                for (int nf = 0; nf < 4; nf++) {
                    float s = 0.f;
#pragma unroll
                    for (int r = 0; r < 4; r++) {
                        const int pos0 = f0 * 16 + ((lane >> 4) << 2) + r;
                        if (pos0 < ce) s += fmaxf(acc0[nf][r] + bb[nf], 0.f);
                    }
                    if (two) {
#pragma unroll
                        for (int r = 0; r < 4; r++) {
                            const int pos1 = (f0 + 1) * 16 + ((lane >> 4) << 2) + r;
                            if (pos1 < ce) s += fmaxf(acc1[nf][r] + bb[nf], 0.f);
                        }
                    }
                    s += __shfl_xor(s, 16, 64);
                    s += __shfl_xor(s, 32, 64);
                    if (lane < 16) rsum[nf] += s;
                }
            }
        }
        // direct store (unique writer per (b,e,j,col); ce==0 writes zeros)
        if (lane < 16) {
            float* dst = aggr3 + (size_t)((b * NE + e) * NN + j) * NH + q * 64 + lane;
#pragma unroll
            for (int nf = 0; nf < 4; nf++) dst[nf * 16] = rsum[nf];
        }
    }
}

// ============ Kernel 3: decoder, 8 j's per block (weight reuse x8) ============
__global__ __launch_bounds__(256) void dec_kernel(
    const float* __restrict__ ns,
    const float* __restrict__ aggr3,
    const float* __restrict__ Wd1, const float* __restrict__ bd1,
    const float* __restrict__ Wd2, const float* __restrict__ bd2,
    float* __restrict__ out)
{
    const int b = blockIdx.x >> 4;
    const int jg = blockIdx.x & 15;
    const int tid = threadIdx.x;
    __shared__ __align__(16) float xs[8][320];
    __shared__ __align__(16) float o1s[8][NH];

    // stage x = [ns(64) | sum_e aggr3(256)] for 8 j's
    for (int x = tid; x < 8 * 320; x += 256) {
        const int jj = x / 320, k = x % 320;
        const int j = jg * 8 + jj;
        float v;
        if (k < ND) v = ns[(size_t)(b * NN + j) * ND + k];
        else {
            const int c = k - ND;
            v = aggr3[(size_t)((b * NE + 0) * NN + j) * NH + c]
              + aggr3[(size_t)((b * NE + 1) * NN + j) * NH + c]
              + aggr3[(size_t)((b * NE + 2) * NN + j) * NH + c];
        }
        xs[jj][k] = v;
    }
    __syncthreads();
    // layer 1: thread owns col n; 8 j's share each weight load
    {
        const int n = tid;
        float acc[8];
        const float b1 = bd1[n];
#pragma unroll
        for (int jj = 0; jj < 8; jj++) acc[jj] = b1;
        for (int k4 = 0; k4 < 80; k4++) {
            const float w0 = Wd1[(size_t)(k4 * 4 + 0) * NH + n];
            const float w1 = Wd1[(size_t)(k4 * 4 + 1) * NH + n];
            const float w2 = Wd1[(size_t)(k4 * 4 + 2) * NH + n];
            const float w3 = Wd1[(size_t)(k4 * 4 + 3) * NH + n];
#pragma unroll
            for (int jj = 0; jj < 8; jj++) {
                const float4 xv = *(const float4*)(&xs[jj][k4 * 4]);
                acc[jj] = fmaf(xv.x, w0, fmaf(xv.y, w1, fmaf(xv.z, w2, fmaf(xv.w, w3, acc[jj]))));
            }
        }
#pragma unroll
        for (int jj = 0; jj < 8; jj++) o1s[jj][n] = fmaxf(acc[jj], 0.f);
    }
    __syncthreads();
    // layer 2: thread = (jj, 2 cols)
    {
        const int jj = tid >> 5, cp = tid & 31;
        const int n0 = cp * 2;
        float a0 = bd2[n0], a1 = bd2[n0 + 1];
        for (int h4 = 0; h4 < 64; h4++) {
            const float4 ov = *(const float4*)(&o1s[jj][h4 * 4]);
            a0 = fmaf(ov.x, Wd2[(size_t)(h4 * 4 + 0) * NOUT + n0], a0);
            a1 = fmaf(ov.x, Wd2[(size_t)(h4 * 4 + 0) * NOUT + n0 + 1], a1);
            a0 = fmaf(ov.y, Wd2[(size_t)(h4 * 4 + 1) * NOUT + n0], a0);
            a1 = fmaf(ov.y, Wd2[(size_t)(h4 * 4 + 1) * NOUT + n0 + 1], a1);
            a0 = fmaf(ov.z, Wd2[(size_t)(h4 * 4 + 2) * NOUT + n0], a0);
            a1 = fmaf(ov.z, Wd2[(size_t)(h4 * 4 + 2) * NOUT + n0 + 1], a1);
            a0 = fmaf(ov.w, Wd2[(size_t)(h4 * 4 + 3) * NOUT + n0], a0);
            a1 = fmaf(ov.w, Wd2[(size_t)(h4 * 4 + 3) * NOUT + n0 + 1], a1);
        }
        const int j = jg * 8 + jj;
        out[(size_t)(b * NN + j) * NOUT + n0] = fmaxf(a0, 0.f);
        out[(size_t)(b * NN + j) * NOUT + n0 + 1] = fmaxf(a1, 0.f);
    }
}

extern "C" void kernel_launch(void* const* d_in, const int* in_sizes, int n_in,
                              void* d_out, int out_size, void* d_ws, size_t ws_size,
                              hipStream_t stream)
{
    const float* ns    = (const float*)d_in[0];
    const float* edges = (const float*)d_in[1];
    const float* We1   = (const float*)d_in[2];
    const float* be1   = (const float*)d_in[3];
    const float* We2   = (const float*)d_in[4];
    const float* be2   = (const float*)d_in[5];
    const float* Wd1   = (const float*)d_in[6];
    const float* bd1   = (const float*)d_in[7];
    const float* Wd2   = (const float*)d_in[8];
    const float* bd2   = (const float*)d_in[9];
    float* outp = (float*)d_out;

    // ws layout (~6.6 MB)
    ushort_t* Pbf  = (ushort_t*)d_ws;                       // 786432
    ushort_t* Qbf  = Pbf + (size_t)NB * NE * NN * NH;       // 786432
    ushort_t* We2t = Qbf + (size_t)NB * NE * NN * NH;       // 196608
    ushort_t* list_ws = We2t + (size_t)NE * NH * NH;        // 131072
    int4* cnts_ws = (int4*)(list_ws + (size_t)NB * NN * NN);// 1024 int4
    float* aggr3 = (float*)(cnts_ws + NB * NN);             // 786432 f32

    hipLaunchKernelGGL(prep_kernel, dim3(1408), dim3(256), 0, stream,
                       We2, ns, We1, be1, edges, We2t, Pbf, Qbf, list_ws, cnts_ws);
    hipLaunchKernelGGL(gemm_kernel, dim3(1536), dim3(256), 0, stream,
                       Pbf, Qbf, We2t, be2, list_ws, cnts_ws, aggr3);
    hipLaunchKernelGGL(dec_kernel, dim3(NB * 16), dim3(256), 0, stream,
                       ns, aggr3, Wd1, bd1, Wd2, bd2, outp);
}

// Round 12
// 143.371 us; speedup vs baseline: 4.3705x; 1.0880x over previous
//
#include <hip/hip_runtime.h>

#define NB 8
#define NN 128
#define ND 64
#define NE 3
#define NH 256
#define NOUT 64

typedef short bf16x8_t __attribute__((ext_vector_type(8)));
typedef float f32x4_t __attribute__((ext_vector_type(4)));
typedef unsigned short ushort_t;

static __device__ __forceinline__ unsigned short f2bf(float f) {
    unsigned u = __float_as_uint(f);
    u += 0x7FFFu + ((u >> 16) & 1u);
    return (unsigned short)(u >> 16);
}
static __device__ __forceinline__ unsigned pk2bf(float a, float b) {
    return (unsigned)f2bf(a) | ((unsigned)f2bf(b) << 16);
}
static __device__ __forceinline__ float bflo(unsigned u) { return __uint_as_float(u << 16); }
static __device__ __forceinline__ float bfhi(unsigned u) { return __uint_as_float(u & 0xffff0000u); }

// A-fragment gen: relu(P + Q) in f32, round to bf16, pack to bf16x8
static __device__ __forceinline__ bf16x8_t a_gen(uint4 pv, uint4 qv) {
    union { uint4 u; bf16x8_t v; } r;
    const float f0 = fmaxf(bflo(pv.x) + bflo(qv.x), 0.f);
    const float f1 = fmaxf(bfhi(pv.x) + bfhi(qv.x), 0.f);
    const float f2 = fmaxf(bflo(pv.y) + bflo(qv.y), 0.f);
    const float f3 = fmaxf(bfhi(pv.y) + bfhi(qv.y), 0.f);
    const float f4 = fmaxf(bflo(pv.z) + bflo(qv.z), 0.f);
    const float f5 = fmaxf(bfhi(pv.z) + bfhi(qv.z), 0.f);
    const float f6 = fmaxf(bflo(pv.w) + bflo(qv.w), 0.f);
    const float f7 = fmaxf(bfhi(pv.w) + bfhi(qv.w), 0.f);
    r.u.x = pk2bf(f0, f1); r.u.y = pk2bf(f2, f3);
    r.u.z = pk2bf(f4, f5); r.u.w = pk2bf(f6, f7);
    return r.v;
}

// ============ Kernel 1: We2p pack (0..47) + P/Q (48..239) + edge pack (240..1263) ============
// We2p layout (ushorts): [((e*16 + nf_g)*8 + kk)*512 + lane*8 + jj]
//   = bf16(We2[e][k = kk*32 + (lane>>4)*8 + jj][n = nf_g*16 + (lane&15)])
// -> gemm B-load is base + lane*16B, fully coalesced.
#define IT 16
__global__ __launch_bounds__(256) void prep_kernel(
    const float* __restrict__ We2, const float* __restrict__ ns,
    const float* __restrict__ We1, const float* __restrict__ be1,
    const float* __restrict__ edges,
    ushort_t* __restrict__ We2p,
    ushort_t* __restrict__ P, ushort_t* __restrict__ Q,
    ushort_t* __restrict__ list_ws, int4* __restrict__ cnts_ws)
{
    const int t = threadIdx.x;
    const int blk = blockIdx.x;

    if (blk < 48) {             // ---- We2p fragment pack ----
        __shared__ float slab[256][16];     // column slab We2[e][:, n0..n0+15]
        const int e = blk >> 4, nfg = blk & 15;
        const int n0 = nfg * 16;
#pragma unroll
        for (int it = 0; it < 16; it++) {
            const int k = (t >> 4) + it * 16;
            slab[k][t & 15] = We2[((size_t)e * NH + k) * NH + n0 + (t & 15)];
        }
        __syncthreads();
        ushort_t* dst = We2p + ((size_t)e * 16 + nfg) * 4096;
#pragma unroll
        for (int it = 0; it < 16; it++) {
            const int idx = it * 256 + t;
            const int kk = idx >> 9;
            const int ln = (idx >> 3) & 63;
            const int jj = idx & 7;
            const int k = kk * 32 + (ln >> 4) * 8 + jj;
            dst[idx] = f2bf(slab[k][ln & 15]);
        }
        return;
    }
    if (blk < 240) {            // ---- P/Q precompute -> bf16 ----
        __shared__ float ns_lds[IT][ND];
        const int blk2 = blk - 48;
        const int itile = blk2 & 7;
        const int e = (blk2 >> 3) % NE;
        const int b = blk2 / 24;
        const int i0 = itile * IT;
        for (int x = t; x < IT * ND; x += 256)
            ns_lds[x / ND][x % ND] = ns[(size_t)(b * NN + i0 + x / ND) * ND + (x % ND)];
        __syncthreads();
        const int h = t;
        float accP[IT], accQ[IT];
        const float bias = be1[e * NH + h];
#pragma unroll
        for (int m = 0; m < IT; m++) { accP[m] = 0.f; accQ[m] = bias; }
        const float* W1 = We1 + (size_t)e * 2 * ND * NH + h;
        for (int d = 0; d < ND; d++) {
            const float w1 = W1[(size_t)d * NH];
            const float w2 = W1[(size_t)(ND + d) * NH];
#pragma unroll
            for (int m = 0; m < IT; m++) {
                accP[m] = fmaf(ns_lds[m][d], w1, accP[m]);
                accQ[m] = fmaf(ns_lds[m][d], w2, accQ[m]);
            }
        }
#pragma unroll
        for (int m = 0; m < IT; m++) {
            const size_t idx = ((size_t)((b * NE + e) * NN) + i0 + m) * NH + h;
            P[idx] = f2bf(accP[m]);
            Q[idx] = f2bf(accQ[m]);
        }
        return;
    }
    // ---- edge pack: per (b,j): bucketed source lists by edge type ----
    {
        __shared__ unsigned long long wm[2][NE];
        const int pb = blk - 240;
        const int b = pb >> 7, j = pb & 127;
        const int lane = t & 63, wave = t >> 6;
        int ecls = -1;
        if (t < 128) {
            const float4 ev = *(const float4*)(edges + ((size_t)(b * NN + t) * NN + j) * 4);
            ecls = ev.y > 0.5f ? 0 : (ev.z > 0.5f ? 1 : (ev.w > 0.5f ? 2 : -1));
#pragma unroll
            for (int ee = 0; ee < NE; ee++) {
                unsigned long long m = __ballot(ecls == ee);
                if (lane == 0) wm[wave][ee] = m;
            }
        }
        __syncthreads();
        const int c0 = __popcll(wm[0][0]) + __popcll(wm[1][0]);
        const int c1 = __popcll(wm[0][1]) + __popcll(wm[1][1]);
        const int c2 = __popcll(wm[0][2]) + __popcll(wm[1][2]);
        if (t < 128 && ecls >= 0) {
            const unsigned long long lower = (1ull << lane) - 1ull;
            int pos = __popcll(wm[wave][ecls] & lower);
            if (wave == 1) pos += __popcll(wm[0][ecls]);
            pos += (ecls > 0 ? c0 : 0) + (ecls > 1 ? c1 : 0);
            list_ws[(size_t)pb * NN + pos] = (ushort_t)t;
        }
        if (t == 0) { int4 cc; cc.x = c0; cc.y = c1; cc.z = c2; cc.w = 0; cnts_ws[pb] = cc; }
    }
}

// ============ Kernel 2: barrier-free masked GEMM; wave = (1 j) x 128-col half ============
__global__ __launch_bounds__(256) void gemm_kernel(
    const ushort_t* __restrict__ Pbf,
    const ushort_t* __restrict__ Qbf,
    const ushort_t* __restrict__ We2p,
    const float* __restrict__ be2,
    const ushort_t* __restrict__ list_ws,
    const int4* __restrict__ cnts_ws,
    float* __restrict__ aggr3)
{
    // grid: 1536 = b(8) x e(3) x jq(32) x nh(2); wave owns j = jq*4 + wave
    const int blk = blockIdx.x;
    const int nh = blk & 1;
    const int jq = (blk >> 1) & 31;
    const int e  = (blk >> 6) % 3;
    const int b  = blk / 192;
    const int lane = threadIdx.x & 63;
    const int wave = threadIdx.x >> 6;
    const int j = jq * 4 + wave;

    const int4 cc = cnts_ws[b * NN + j];
    const int ce = e == 0 ? cc.x : (e == 1 ? cc.y : cc.z);
    const int start = (e > 0 ? cc.x : 0) + (e > 1 ? cc.y : 0);
    const ushort_t* Lj = list_ws + (size_t)(b * NN + j) * NN + start;
    const ushort_t* Qj = Qbf + (size_t)((b * NE + e) * NN + j) * NH;
    const ushort_t* Pb = Pbf + (size_t)(b * NE + e) * NN * NH;
    const ushort_t* Bp = We2p + ((size_t)e * 16 + nh * 8) * 4096;   // 8 nf tiles x 4096 ushorts

    float bb[8];
#pragma unroll
    for (int nf = 0; nf < 8; nf++)
        bb[nf] = be2[e * NH + nh * 128 + nf * 16 + (lane & 15)];

    float rsum[8] = {0.f, 0.f, 0.f, 0.f, 0.f, 0.f, 0.f, 0.f};
    if (ce > 0) {
        const int F = (ce + 15) >> 4;
        for (int f0 = 0; f0 < F; f0 += 2) {
            const bool two = (f0 + 1) < F;
            int p0 = f0 * 16 + (lane & 15);        p0 = p0 < ce ? p0 : ce - 1;
            int p1 = (f0 + 1) * 16 + (lane & 15);  p1 = p1 < ce ? p1 : ce - 1;
            const ushort_t* P0 = Pb + (size_t)Lj[p0] * NH;
            const ushort_t* P1 = Pb + (size_t)Lj[p1] * NH;

            f32x4_t acc0[8], acc1[8];
            const f32x4_t z4 = {0.f, 0.f, 0.f, 0.f};
#pragma unroll
            for (int nf = 0; nf < 8; nf++) { acc0[nf] = z4; acc1[nf] = z4; }

#pragma unroll 2
            for (int kk = 0; kk < 8; kk++) {
                const int ko = kk * 32 + (lane >> 4) * 8;
                const uint4 qv = *(const uint4*)(Qj + ko);
                const bf16x8_t af0 = a_gen(*(const uint4*)(P0 + ko), qv);
                bf16x8_t af1 = af0;
                if (two) af1 = a_gen(*(const uint4*)(P1 + ko), qv);
#pragma unroll
                for (int nf = 0; nf < 8; nf++) {
                    // fully coalesced: 64 lanes x 16B sequential
                    const bf16x8_t bfr = *(const bf16x8_t*)(Bp + ((size_t)nf * 8 + kk) * 512 + lane * 8);
                    acc0[nf] = __builtin_amdgcn_mfma_f32_16x16x32_bf16(af0, bfr, acc0[nf], 0, 0, 0);
                    if (two)
                        acc1[nf] = __builtin_amdgcn_mfma_f32_16x16x32_bf16(af1, bfr, acc1[nf], 0, 0, 0);
                }
            }
            // epilogue: bias+relu+row-mask, cross-lane col reduce
#pragma unroll
            for (int nf = 0; nf < 8; nf++) {
                float s = 0.f;
#pragma unroll
                for (int r = 0; r < 4; r++) {
                    const int pos0 = f0 * 16 + ((lane >> 4) << 2) + r;
                    if (pos0 < ce) s += fmaxf(acc0[nf][r] + bb[nf], 0.f);
                }
                if (two) {
#pragma unroll
                    for (int r = 0; r < 4; r++) {
                        const int pos1 = (f0 + 1) * 16 + ((lane >> 4) << 2) + r;
                        if (pos1 < ce) s += fmaxf(acc1[nf][r] + bb[nf], 0.f);
                    }
                }
                s += __shfl_xor(s, 16, 64);
                s += __shfl_xor(s, 32, 64);
                if (lane < 16) rsum[nf] += s;
            }
        }
    }
    // direct store (unique writer per (b,e,j,col); ce==0 writes zeros)
    if (lane < 16) {
        float* dst = aggr3 + (size_t)((b * NE + e) * NN + j) * NH + nh * 128 + lane;
#pragma unroll
        for (int nf = 0; nf < 8; nf++) dst[nf * 16] = rsum[nf];
    }
}

// ============ Kernel 3: decoder, 8 j's per block (weight reuse x8) ============
__global__ __launch_bounds__(256) void dec_kernel(
    const float* __restrict__ ns,
    const float* __restrict__ aggr3,
    const float* __restrict__ Wd1, const float* __restrict__ bd1,
    const float* __restrict__ Wd2, const float* __restrict__ bd2,
    float* __restrict__ out)
{
    const int b = blockIdx.x >> 4;
    const int jg = blockIdx.x & 15;
    const int tid = threadIdx.x;
    __shared__ __align__(16) float xs[8][320];
    __shared__ __align__(16) float o1s[8][NH];

    // stage x = [ns(64) | sum_e aggr3(256)] for 8 j's
    for (int x = tid; x < 8 * 320; x += 256) {
        const int jj = x / 320, k = x % 320;
        const int j = jg * 8 + jj;
        float v;
        if (k < ND) v = ns[(size_t)(b * NN + j) * ND + k];
        else {
            const int c = k - ND;
            v = aggr3[(size_t)((b * NE + 0) * NN + j) * NH + c]
              + aggr3[(size_t)((b * NE + 1) * NN + j) * NH + c]
              + aggr3[(size_t)((b * NE + 2) * NN + j) * NH + c];
        }
        xs[jj][k] = v;
    }
    __syncthreads();
    // layer 1: thread owns col n; 8 j's share each weight load
    {
        const int n = tid;
        float acc[8];
        const float b1 = bd1[n];
#pragma unroll
        for (int jj = 0; jj < 8; jj++) acc[jj] = b1;
        for (int k4 = 0; k4 < 80; k4++) {
            const float w0 = Wd1[(size_t)(k4 * 4 + 0) * NH + n];
            const float w1 = Wd1[(size_t)(k4 * 4 + 1) * NH + n];
            const float w2 = Wd1[(size_t)(k4 * 4 + 2) * NH + n];
            const float w3 = Wd1[(size_t)(k4 * 4 + 3) * NH + n];
#pragma unroll
            for (int jj = 0; jj < 8; jj++) {
                const float4 xv = *(const float4*)(&xs[jj][k4 * 4]);
                acc[jj] = fmaf(xv.x, w0, fmaf(xv.y, w1, fmaf(xv.z, w2, fmaf(xv.w, w3, acc[jj]))));
            }
        }
#pragma unroll
        for (int jj = 0; jj < 8; jj++) o1s[jj][n] = fmaxf(acc[jj], 0.f);
    }
    __syncthreads();
    // layer 2: thread = (jj, 2 cols)
    {
        const int jj = tid >> 5, cp = tid & 31;
        const int n0 = cp * 2;
        float a0 = bd2[n0], a1 = bd2[n0 + 1];
        for (int h4 = 0; h4 < 64; h4++) {
            const float4 ov = *(const float4*)(&o1s[jj][h4 * 4]);
            a0 = fmaf(ov.x, Wd2[(size_t)(h4 * 4 + 0) * NOUT + n0], a0);
            a1 = fmaf(ov.x, Wd2[(size_t)(h4 * 4 + 0) * NOUT + n0 + 1], a1);
            a0 = fmaf(ov.y, Wd2[(size_t)(h4 * 4 + 1) * NOUT + n0], a0);
            a1 = fmaf(ov.y, Wd2[(size_t)(h4 * 4 + 1) * NOUT + n0 + 1], a1);
            a0 = fmaf(ov.z, Wd2[(size_t)(h4 * 4 + 2) * NOUT + n0], a0);
            a1 = fmaf(ov.z, Wd2[(size_t)(h4 * 4 + 2) * NOUT + n0 + 1], a1);
            a0 = fmaf(ov.w, Wd2[(size_t)(h4 * 4 + 3) * NOUT + n0], a0);
            a1 = fmaf(ov.w, Wd2[(size_t)(h4 * 4 + 3) * NOUT + n0 + 1], a1);
        }
        const int j = jg * 8 + jj;
        out[(size_t)(b * NN + j) * NOUT + n0] = fmaxf(a0, 0.f);
        out[(size_t)(b * NN + j) * NOUT + n0 + 1] = fmaxf(a1, 0.f);
    }
}

extern "C" void kernel_launch(void* const* d_in, const int* in_sizes, int n_in,
                              void* d_out, int out_size, void* d_ws, size_t ws_size,
                              hipStream_t stream)
{
    const float* ns    = (const float*)d_in[0];
    const float* edges = (const float*)d_in[1];
    const float* We1   = (const float*)d_in[2];
    const float* be1   = (const float*)d_in[3];
    const float* We2   = (const float*)d_in[4];
    const float* be2   = (const float*)d_in[5];
    const float* Wd1   = (const float*)d_in[6];
    const float* bd1   = (const float*)d_in[7];
    const float* Wd2   = (const float*)d_in[8];
    const float* bd2   = (const float*)d_in[9];
    float* outp = (float*)d_out;

    // ws layout (~6.6 MB)
    ushort_t* Pbf  = (ushort_t*)d_ws;                       // 786432
    ushort_t* Qbf  = Pbf + (size_t)NB * NE * NN * NH;       // 786432
    ushort_t* We2p = Qbf + (size_t)NB * NE * NN * NH;       // 196608
    ushort_t* list_ws = We2p + (size_t)NE * NH * NH;        // 131072
    int4* cnts_ws = (int4*)(list_ws + (size_t)NB * NN * NN);// 1024 int4
    float* aggr3 = (float*)(cnts_ws + NB * NN);             // 786432 f32

    hipLaunchKernelGGL(prep_kernel, dim3(1264), dim3(256), 0, stream,
                       We2, ns, We1, be1, edges, We2p, Pbf, Qbf, list_ws, cnts_ws);
    hipLaunchKernelGGL(gemm_kernel, dim3(1536), dim3(256), 0, stream,
                       Pbf, Qbf, We2p, be2, list_ws, cnts_ws, aggr3);
    hipLaunchKernelGGL(dec_kernel, dim3(NB * 16), dim3(256), 0, stream,
                       ns, aggr3, Wd1, bd1, Wd2, bd2, outp);
}

// Round 13
// 118.701 us; speedup vs baseline: 5.2788x; 1.2078x over previous
//
#include <hip/hip_runtime.h>

#define NB 8
#define NN 128
#define ND 64
#define NE 3
#define NH 256
#define NOUT 64

typedef short bf16x8_t __attribute__((ext_vector_type(8)));
typedef float f32x4_t __attribute__((ext_vector_type(4)));
typedef unsigned short ushort_t;

static __device__ __forceinline__ unsigned short f2bf(float f) {
    unsigned u = __float_as_uint(f);
    u += 0x7FFFu + ((u >> 16) & 1u);
    return (unsigned short)(u >> 16);
}
static __device__ __forceinline__ unsigned pk2bf(float a, float b) {
    return (unsigned)f2bf(a) | ((unsigned)f2bf(b) << 16);
}
static __device__ __forceinline__ float bflo(unsigned u) { return __uint_as_float(u << 16); }
static __device__ __forceinline__ float bfhi(unsigned u) { return __uint_as_float(u & 0xffff0000u); }

// A-fragment gen: relu(P + Q) in f32, round to bf16, pack to bf16x8
static __device__ __forceinline__ bf16x8_t a_gen(uint4 pv, uint4 qv) {
    union { uint4 u; bf16x8_t v; } r;
    const float f0 = fmaxf(bflo(pv.x) + bflo(qv.x), 0.f);
    const float f1 = fmaxf(bfhi(pv.x) + bfhi(qv.x), 0.f);
    const float f2 = fmaxf(bflo(pv.y) + bflo(qv.y), 0.f);
    const float f3 = fmaxf(bfhi(pv.y) + bfhi(qv.y), 0.f);
    const float f4 = fmaxf(bflo(pv.z) + bflo(qv.z), 0.f);
    const float f5 = fmaxf(bfhi(pv.z) + bfhi(qv.z), 0.f);
    const float f6 = fmaxf(bflo(pv.w) + bflo(qv.w), 0.f);
    const float f7 = fmaxf(bfhi(pv.w) + bfhi(qv.w), 0.f);
    r.u.x = pk2bf(f0, f1); r.u.y = pk2bf(f2, f3);
    r.u.z = pk2bf(f4, f5); r.u.w = pk2bf(f6, f7);
    return r.v;
}

// ============ Kernel 1: We2p pack (0..47) + P/Q (48..239) + edge pack (240..1263) ============
// We2p layout (ushorts): [((e*16 + nf_g)*8 + kk)*512 + lane*8 + jj]
//   = bf16(We2[e][k = kk*32 + (lane>>4)*8 + jj][n = nf_g*16 + (lane&15)])
#define IT 16
__global__ __launch_bounds__(256) void prep_kernel(
    const float* __restrict__ We2, const float* __restrict__ ns,
    const float* __restrict__ We1, const float* __restrict__ be1,
    const float* __restrict__ edges,
    ushort_t* __restrict__ We2p,
    ushort_t* __restrict__ P, ushort_t* __restrict__ Q,
    ushort_t* __restrict__ list_ws, int4* __restrict__ cnts_ws)
{
    const int t = threadIdx.x;
    const int blk = blockIdx.x;

    if (blk < 48) {             // ---- We2p fragment pack ----
        __shared__ float slab[256][16];     // column slab We2[e][:, n0..n0+15]
        const int e = blk >> 4, nfg = blk & 15;
        const int n0 = nfg * 16;
#pragma unroll
        for (int it = 0; it < 16; it++) {
            const int k = (t >> 4) + it * 16;
            slab[k][t & 15] = We2[((size_t)e * NH + k) * NH + n0 + (t & 15)];
        }
        __syncthreads();
        ushort_t* dst = We2p + ((size_t)e * 16 + nfg) * 4096;
#pragma unroll
        for (int it = 0; it < 16; it++) {
            const int idx = it * 256 + t;
            const int kk = idx >> 9;
            const int ln = (idx >> 3) & 63;
            const int jj = idx & 7;
            const int k = kk * 32 + (ln >> 4) * 8 + jj;
            dst[idx] = f2bf(slab[k][ln & 15]);
        }
        return;
    }
    if (blk < 240) {            // ---- P/Q precompute -> bf16 ----
        __shared__ float ns_lds[IT][ND];
        const int blk2 = blk - 48;
        const int itile = blk2 & 7;
        const int e = (blk2 >> 3) % NE;
        const int b = blk2 / 24;
        const int i0 = itile * IT;
        for (int x = t; x < IT * ND; x += 256)
            ns_lds[x / ND][x % ND] = ns[(size_t)(b * NN + i0 + x / ND) * ND + (x % ND)];
        __syncthreads();
        const int h = t;
        float accP[IT], accQ[IT];
        const float bias = be1[e * NH + h];
#pragma unroll
        for (int m = 0; m < IT; m++) { accP[m] = 0.f; accQ[m] = bias; }
        const float* W1 = We1 + (size_t)e * 2 * ND * NH + h;
        for (int d = 0; d < ND; d++) {
            const float w1 = W1[(size_t)d * NH];
            const float w2 = W1[(size_t)(ND + d) * NH];
#pragma unroll
            for (int m = 0; m < IT; m++) {
                accP[m] = fmaf(ns_lds[m][d], w1, accP[m]);
                accQ[m] = fmaf(ns_lds[m][d], w2, accQ[m]);
            }
        }
#pragma unroll
        for (int m = 0; m < IT; m++) {
            const size_t idx = ((size_t)((b * NE + e) * NN) + i0 + m) * NH + h;
            P[idx] = f2bf(accP[m]);
            Q[idx] = f2bf(accQ[m]);
        }
        return;
    }
    // ---- edge pack: per (b,j): bucketed source lists by edge type ----
    {
        __shared__ unsigned long long wm[2][NE];
        const int pb = blk - 240;
        const int b = pb >> 7, j = pb & 127;
        const int lane = t & 63, wave = t >> 6;
        int ecls = -1;
        if (t < 128) {
            const float4 ev = *(const float4*)(edges + ((size_t)(b * NN + t) * NN + j) * 4);
            ecls = ev.y > 0.5f ? 0 : (ev.z > 0.5f ? 1 : (ev.w > 0.5f ? 2 : -1));
#pragma unroll
            for (int ee = 0; ee < NE; ee++) {
                unsigned long long m = __ballot(ecls == ee);
                if (lane == 0) wm[wave][ee] = m;
            }
        }
        __syncthreads();
        const int c0 = __popcll(wm[0][0]) + __popcll(wm[1][0]);
        const int c1 = __popcll(wm[0][1]) + __popcll(wm[1][1]);
        const int c2 = __popcll(wm[0][2]) + __popcll(wm[1][2]);
        if (t < 128 && ecls >= 0) {
            const unsigned long long lower = (1ull << lane) - 1ull;
            int pos = __popcll(wm[wave][ecls] & lower);
            if (wave == 1) pos += __popcll(wm[0][ecls]);
            pos += (ecls > 0 ? c0 : 0) + (ecls > 1 ? c1 : 0);
            list_ws[(size_t)pb * NN + pos] = (ushort_t)t;
        }
        if (t == 0) { int4 cc; cc.x = c0; cc.y = c1; cc.z = c2; cc.w = 0; cnts_ws[pb] = cc; }
    }
}

// ============ Kernel 2: LDS-B masked GEMM; block = (b,e, 8 j's, 128-col half) ============
__global__ __launch_bounds__(256) void gemm_kernel(
    const ushort_t* __restrict__ Pbf,
    const ushort_t* __restrict__ Qbf,
    const ushort_t* __restrict__ We2p,
    const float* __restrict__ be2,
    const ushort_t* __restrict__ list_ws,
    const int4* __restrict__ cnts_ws,
    float* __restrict__ aggr3)
{
    // grid: 768 = b(8) x e(3) x jg(16) x nh(2); wave owns j = jg*8 + wave*2 + {0,1}
    const int blk = blockIdx.x;
    const int nh = blk & 1;
    const int jg = (blk >> 1) & 15;
    const int e  = (blk >> 5) % 3;
    const int b  = blk / 96;
    const int tid = threadIdx.x;
    const int lane = tid & 63;
    const int wave = tid >> 6;

    __shared__ __align__(16) ushort_t Bl[8 * 8 * 512];   // [nf][kk][512] = 64 KB

    // ---- one-time B stage: linear 64 KB L2 -> LDS, fully coalesced ----
    {
        const ushort_t* Bsrc = We2p + ((size_t)e * 16 + nh * 8) * 4096;
#pragma unroll
        for (int it = 0; it < 16; it++) {
            const int o = it * 2048 + tid * 8;
            *(uint4*)&Bl[o] = *(const uint4*)&Bsrc[o];
        }
    }

    float bb[8];
#pragma unroll
    for (int nf = 0; nf < 8; nf++)
        bb[nf] = be2[e * NH + nh * 128 + nf * 16 + (lane & 15)];
    const ushort_t* Pb = Pbf + (size_t)(b * NE + e) * NN * NH;

    __syncthreads();   // Bl visible; only barrier in the kernel

    for (int jj = 0; jj < 2; jj++) {
        const int j = jg * 8 + wave * 2 + jj;
        const int4 cc = cnts_ws[b * NN + j];
        const int ce = e == 0 ? cc.x : (e == 1 ? cc.y : cc.z);
        const int start = (e > 0 ? cc.x : 0) + (e > 1 ? cc.y : 0);
        const ushort_t* Lj = list_ws + (size_t)(b * NN + j) * NN + start;
        const ushort_t* Qj = Qbf + (size_t)((b * NE + e) * NN + j) * NH;

        float rsum[8] = {0.f, 0.f, 0.f, 0.f, 0.f, 0.f, 0.f, 0.f};
        if (ce > 0) {
            const int F = (ce + 15) >> 4;
            for (int f0 = 0; f0 < F; f0 += 2) {
                const bool two = (f0 + 1) < F;
                int p0 = f0 * 16 + (lane & 15);        p0 = p0 < ce ? p0 : ce - 1;
                int p1 = (f0 + 1) * 16 + (lane & 15);  p1 = p1 < ce ? p1 : ce - 1;
                const ushort_t* P0 = Pb + (size_t)Lj[p0] * NH;
                const ushort_t* P1 = Pb + (size_t)Lj[p1] * NH;

                f32x4_t acc0[8], acc1[8];
                const f32x4_t z4 = {0.f, 0.f, 0.f, 0.f};
#pragma unroll
                for (int nf = 0; nf < 8; nf++) { acc0[nf] = z4; acc1[nf] = z4; }

#pragma unroll 2
                for (int kk = 0; kk < 8; kk++) {
                    const int ko = kk * 32 + (lane >> 4) * 8;
                    const uint4 qv = *(const uint4*)(Qj + ko);
                    const bf16x8_t af0 = a_gen(*(const uint4*)(P0 + ko), qv);
                    bf16x8_t af1 = af0;
                    if (two) af1 = a_gen(*(const uint4*)(P1 + ko), qv);
#pragma unroll
                    for (int nf = 0; nf < 8; nf++) {
                        const bf16x8_t bfr = *(const bf16x8_t*)(&Bl[(nf * 8 + kk) * 512 + lane * 8]);
                        acc0[nf] = __builtin_amdgcn_mfma_f32_16x16x32_bf16(af0, bfr, acc0[nf], 0, 0, 0);
                        if (two)
                            acc1[nf] = __builtin_amdgcn_mfma_f32_16x16x32_bf16(af1, bfr, acc1[nf], 0, 0, 0);
                    }
                }
                // epilogue: bias+relu+row-mask, cross-lane col reduce
#pragma unroll
                for (int nf = 0; nf < 8; nf++) {
                    float s = 0.f;
#pragma unroll
                    for (int r = 0; r < 4; r++) {
                        const int pos0 = f0 * 16 + ((lane >> 4) << 2) + r;
                        if (pos0 < ce) s += fmaxf(acc0[nf][r] + bb[nf], 0.f);
                    }
                    if (two) {
#pragma unroll
                        for (int r = 0; r < 4; r++) {
                            const int pos1 = (f0 + 1) * 16 + ((lane >> 4) << 2) + r;
                            if (pos1 < ce) s += fmaxf(acc1[nf][r] + bb[nf], 0.f);
                        }
                    }
                    s += __shfl_xor(s, 16, 64);
                    s += __shfl_xor(s, 32, 64);
                    if (lane < 16) rsum[nf] += s;
                }
            }
        }
        // direct store (unique writer per (b,e,j,col); ce==0 writes zeros)
        if (lane < 16) {
            float* dst = aggr3 + (size_t)((b * NE + e) * NN + j) * NH + nh * 128 + lane;
#pragma unroll
            for (int nf = 0; nf < 8; nf++) dst[nf * 16] = rsum[nf];
        }
    }
}

// ============ Kernel 3: decoder, 8 j's per block (weight reuse x8) ============
__global__ __launch_bounds__(256) void dec_kernel(
    const float* __restrict__ ns,
    const float* __restrict__ aggr3,
    const float* __restrict__ Wd1, const float* __restrict__ bd1,
    const float* __restrict__ Wd2, const float* __restrict__ bd2,
    float* __restrict__ out)
{
    const int b = blockIdx.x >> 4;
    const int jg = blockIdx.x & 15;
    const int tid = threadIdx.x;
    __shared__ __align__(16) float xs[8][320];
    __shared__ __align__(16) float o1s[8][NH];

    // stage x = [ns(64) | sum_e aggr3(256)] for 8 j's
    for (int x = tid; x < 8 * 320; x += 256) {
        const int jj = x / 320, k = x % 320;
        const int j = jg * 8 + jj;
        float v;
        if (k < ND) v = ns[(size_t)(b * NN + j) * ND + k];
        else {
            const int c = k - ND;
            v = aggr3[(size_t)((b * NE + 0) * NN + j) * NH + c]
              + aggr3[(size_t)((b * NE + 1) * NN + j) * NH + c]
              + aggr3[(size_t)((b * NE + 2) * NN + j) * NH + c];
        }
        xs[jj][k] = v;
    }
    __syncthreads();
    // layer 1: thread owns col n; 8 j's share each weight load
    {
        const int n = tid;
        float acc[8];
        const float b1 = bd1[n];
#pragma unroll
        for (int jj = 0; jj < 8; jj++) acc[jj] = b1;
        for (int k4 = 0; k4 < 80; k4++) {
            const float w0 = Wd1[(size_t)(k4 * 4 + 0) * NH + n];
            const float w1 = Wd1[(size_t)(k4 * 4 + 1) * NH + n];
            const float w2 = Wd1[(size_t)(k4 * 4 + 2) * NH + n];
            const float w3 = Wd1[(size_t)(k4 * 4 + 3) * NH + n];
#pragma unroll
            for (int jj = 0; jj < 8; jj++) {
                const float4 xv = *(const float4*)(&xs[jj][k4 * 4]);
                acc[jj] = fmaf(xv.x, w0, fmaf(xv.y, w1, fmaf(xv.z, w2, fmaf(xv.w, w3, acc[jj]))));
            }
        }
#pragma unroll
        for (int jj = 0; jj < 8; jj++) o1s[jj][n] = fmaxf(acc[jj], 0.f);
    }
    __syncthreads();
    // layer 2: thread = (jj, 2 cols)
    {
        const int jj = tid >> 5, cp = tid & 31;
        const int n0 = cp * 2;
        float a0 = bd2[n0], a1 = bd2[n0 + 1];
        for (int h4 = 0; h4 < 64; h4++) {
            const float4 ov = *(const float4*)(&o1s[jj][h4 * 4]);
            a0 = fmaf(ov.x, Wd2[(size_t)(h4 * 4 + 0) * NOUT + n0], a0);
            a1 = fmaf(ov.x, Wd2[(size_t)(h4 * 4 + 0) * NOUT + n0 + 1], a1);
            a0 = fmaf(ov.y, Wd2[(size_t)(h4 * 4 + 1) * NOUT + n0], a0);
            a1 = fmaf(ov.y, Wd2[(size_t)(h4 * 4 + 1) * NOUT + n0 + 1], a1);
            a0 = fmaf(ov.z, Wd2[(size_t)(h4 * 4 + 2) * NOUT + n0], a0);
            a1 = fmaf(ov.z, Wd2[(size_t)(h4 * 4 + 2) * NOUT + n0 + 1], a1);
            a0 = fmaf(ov.w, Wd2[(size_t)(h4 * 4 + 3) * NOUT + n0], a0);
            a1 = fmaf(ov.w, Wd2[(size_t)(h4 * 4 + 3) * NOUT + n0 + 1], a1);
        }
        const int j = jg * 8 + jj;
        out[(size_t)(b * NN + j) * NOUT + n0] = fmaxf(a0, 0.f);
        out[(size_t)(b * NN + j) * NOUT + n0 + 1] = fmaxf(a1, 0.f);
    }
}

extern "C" void kernel_launch(void* const* d_in, const int* in_sizes, int n_in,
                              void* d_out, int out_size, void* d_ws, size_t ws_size,
                              hipStream_t stream)
{
    const float* ns    = (const float*)d_in[0];
    const float* edges = (const float*)d_in[1];
    const float* We1   = (const float*)d_in[2];
    const float* be1   = (const float*)d_in[3];
    const float* We2   = (const float*)d_in[4];
    const float* be2   = (const float*)d_in[5];
    const float* Wd1   = (const float*)d_in[6];
    const float* bd1   = (const float*)d_in[7];
    const float* Wd2   = (const float*)d_in[8];
    const float* bd2   = (const float*)d_in[9];
    float* outp = (float*)d_out;

    // ws layout (~6.6 MB)
    ushort_t* Pbf  = (ushort_t*)d_ws;                       // 786432
    ushort_t* Qbf  = Pbf + (size_t)NB * NE * NN * NH;       // 786432
    ushort_t* We2p = Qbf + (size_t)NB * NE * NN * NH;       // 196608
    ushort_t* list_ws = We2p + (size_t)NE * NH * NH;        // 131072
    int4* cnts_ws = (int4*)(list_ws + (size_t)NB * NN * NN);// 1024 int4
    float* aggr3 = (float*)(cnts_ws + NB * NN);             // 786432 f32

    hipLaunchKernelGGL(prep_kernel, dim3(1264), dim3(256), 0, stream,
                       We2, ns, We1, be1, edges, We2p, Pbf, Qbf, list_ws, cnts_ws);
    hipLaunchKernelGGL(gemm_kernel, dim3(768), dim3(256), 0, stream,
                       Pbf, Qbf, We2p, be2, list_ws, cnts_ws, aggr3);
    hipLaunchKernelGGL(dec_kernel, dim3(NB * 16), dim3(256), 0, stream,
                       ns, aggr3, Wd1, bd1, Wd2, bd2, outp);
}

// Round 14
// 83.451 us; speedup vs baseline: 7.5086x; 1.4224x over previous
//
#include <hip/hip_runtime.h>

#define NB 8
#define NN 128
#define ND 64
#define NE 3
#define NH 256
#define NOUT 64

typedef short bf16x8_t __attribute__((ext_vector_type(8)));
typedef float f32x4_t __attribute__((ext_vector_type(4)));
typedef unsigned short ushort_t;

static __device__ __forceinline__ unsigned short f2bf(float f) {
    unsigned u = __float_as_uint(f);
    u += 0x7FFFu + ((u >> 16) & 1u);
    return (unsigned short)(u >> 16);
}
static __device__ __forceinline__ unsigned pk2bf(float a, float b) {
    return (unsigned)f2bf(a) | ((unsigned)f2bf(b) << 16);
}

// A-fragment gen from f32 P,Q: relu(P+Q) -> bf16 pack (8 add + 8 max + 4 pack)
static __device__ __forceinline__ bf16x8_t a_genf(float4 p0, float4 p1, float4 q0, float4 q1) {
    union { uint4 u; bf16x8_t v; } r;
    r.u.x = pk2bf(fmaxf(p0.x + q0.x, 0.f), fmaxf(p0.y + q0.y, 0.f));
    r.u.y = pk2bf(fmaxf(p0.z + q0.z, 0.f), fmaxf(p0.w + q0.w, 0.f));
    r.u.z = pk2bf(fmaxf(p1.x + q1.x, 0.f), fmaxf(p1.y + q1.y, 0.f));
    r.u.w = pk2bf(fmaxf(p1.z + q1.z, 0.f), fmaxf(p1.w + q1.w, 0.f));
    return r.v;
}

// ============ Kernel 1: We2p pack (0..47) + P/Q f32 (48..239) + edge pack (240..1263) ============
// We2p layout (ushorts): [((e*16 + nf)*8 + kk)*512 + lane*8 + jj]
//   = bf16(We2[e][k = kk*32 + (lane>>4)*8 + jj][n = nf*16 + (lane&15)])
#define IT 16
__global__ __launch_bounds__(256) void prep_kernel(
    const float* __restrict__ We2, const float* __restrict__ ns,
    const float* __restrict__ We1, const float* __restrict__ be1,
    const float* __restrict__ edges,
    ushort_t* __restrict__ We2p,
    float* __restrict__ P, float* __restrict__ Q,
    ushort_t* __restrict__ list_ws, int4* __restrict__ cnts_ws)
{
    const int t = threadIdx.x;
    const int blk = blockIdx.x;

    if (blk < 48) {             // ---- We2p fragment pack ----
        __shared__ float slab[256][16];
        const int e = blk >> 4, nfg = blk & 15;
        const int n0 = nfg * 16;
#pragma unroll
        for (int it = 0; it < 16; it++) {
            const int k = (t >> 4) + it * 16;
            slab[k][t & 15] = We2[((size_t)e * NH + k) * NH + n0 + (t & 15)];
        }
        __syncthreads();
        ushort_t* dst = We2p + ((size_t)e * 16 + nfg) * 4096;
#pragma unroll
        for (int it = 0; it < 16; it++) {
            const int idx = it * 256 + t;
            const int kk = idx >> 9;
            const int ln = (idx >> 3) & 63;
            const int jj = idx & 7;
            const int k = kk * 32 + (ln >> 4) * 8 + jj;
            dst[idx] = f2bf(slab[k][ln & 15]);
        }
        return;
    }
    if (blk < 240) {            // ---- P/Q precompute -> f32 ----
        __shared__ float ns_lds[IT][ND];
        const int blk2 = blk - 48;
        const int itile = blk2 & 7;
        const int e = (blk2 >> 3) % NE;
        const int b = blk2 / 24;
        const int i0 = itile * IT;
        for (int x = t; x < IT * ND; x += 256)
            ns_lds[x / ND][x % ND] = ns[(size_t)(b * NN + i0 + x / ND) * ND + (x % ND)];
        __syncthreads();
        const int h = t;
        float accP[IT], accQ[IT];
        const float bias = be1[e * NH + h];
#pragma unroll
        for (int m = 0; m < IT; m++) { accP[m] = 0.f; accQ[m] = bias; }
        const float* W1 = We1 + (size_t)e * 2 * ND * NH + h;
        for (int d = 0; d < ND; d++) {
            const float w1 = W1[(size_t)d * NH];
            const float w2 = W1[(size_t)(ND + d) * NH];
#pragma unroll
            for (int m = 0; m < IT; m++) {
                accP[m] = fmaf(ns_lds[m][d], w1, accP[m]);
                accQ[m] = fmaf(ns_lds[m][d], w2, accQ[m]);
            }
        }
#pragma unroll
        for (int m = 0; m < IT; m++) {
            const size_t idx = ((size_t)((b * NE + e) * NN) + i0 + m) * NH + h;
            P[idx] = accP[m];
            Q[idx] = accQ[m];
        }
        return;
    }
    // ---- edge pack: per (b,j): bucketed source lists by edge type ----
    {
        __shared__ unsigned long long wm[2][NE];
        const int pb = blk - 240;
        const int b = pb >> 7, j = pb & 127;
        const int lane = t & 63, wave = t >> 6;
        int ecls = -1;
        if (t < 128) {
            const float4 ev = *(const float4*)(edges + ((size_t)(b * NN + t) * NN + j) * 4);
            ecls = ev.y > 0.5f ? 0 : (ev.z > 0.5f ? 1 : (ev.w > 0.5f ? 2 : -1));
#pragma unroll
            for (int ee = 0; ee < NE; ee++) {
                unsigned long long m = __ballot(ecls == ee);
                if (lane == 0) wm[wave][ee] = m;
            }
        }
        __syncthreads();
        const int c0 = __popcll(wm[0][0]) + __popcll(wm[1][0]);
        const int c1 = __popcll(wm[0][1]) + __popcll(wm[1][1]);
        const int c2 = __popcll(wm[0][2]) + __popcll(wm[1][2]);
        if (t < 128 && ecls >= 0) {
            const unsigned long long lower = (1ull << lane) - 1ull;
            int pos = __popcll(wm[wave][ecls] & lower);
            if (wave == 1) pos += __popcll(wm[0][ecls]);
            pos += (ecls > 0 ? c0 : 0) + (ecls > 1 ? c1 : 0);
            list_ws[(size_t)pb * NN + pos] = (ushort_t)t;
        }
        if (t == 0) { int4 cc; cc.x = c0; cc.y = c1; cc.z = c2; cc.w = 0; cnts_ws[pb] = cc; }
    }
}

// ============ Kernel 2: full-B-LDS masked GEMM; block = (b,e, 8 j's), wave = 1 j x 256 cols ============
__global__ __launch_bounds__(512) void gemm_kernel(
    const float* __restrict__ Pf,
    const float* __restrict__ Qf,
    const ushort_t* __restrict__ We2p,
    const float* __restrict__ be2,
    const ushort_t* __restrict__ list_ws,
    const int4* __restrict__ cnts_ws,
    float* __restrict__ aggr3)
{
    // grid: 384 = b(8) x e(3) x jg(16); 512 threads = 8 waves; wave owns j = jg*8 + wave
    const int blk = blockIdx.x;
    const int jg = blk & 15;
    const int e  = (blk >> 4) % 3;
    const int b  = blk / 48;
    const int tid = threadIdx.x;
    const int lane = tid & 63;
    const int wave = tid >> 6;

    __shared__ __align__(16) ushort_t Bl[16 * 8 * 512];   // 128 KB: [nf][kk][512]

    {   // ---- one-time B stage: linear 128 KB L2 -> LDS, fully coalesced ----
        const ushort_t* Bsrc = We2p + (size_t)e * 65536;
#pragma unroll
        for (int it = 0; it < 16; it++) {
            const int o = it * 4096 + tid * 8;
            *(uint4*)&Bl[o] = *(const uint4*)&Bsrc[o];
        }
    }

    const int j = jg * 8 + wave;
    const int4 cc = cnts_ws[b * NN + j];
    const int ce = e == 0 ? cc.x : (e == 1 ? cc.y : cc.z);
    const int start = (e > 0 ? cc.x : 0) + (e > 1 ? cc.y : 0);
    const ushort_t* Lj = list_ws + (size_t)(b * NN + j) * NN + start;
    const float* Qj = Qf + (size_t)((b * NE + e) * NN + j) * NH;
    const float* Pb = Pf + (size_t)(b * NE + e) * NN * NH;

    float bb[16];
#pragma unroll
    for (int nf = 0; nf < 16; nf++)
        bb[nf] = be2[e * NH + nf * 16 + (lane & 15)];

    __syncthreads();   // Bl visible; only barrier

    float rsum[16];
#pragma unroll
    for (int nf = 0; nf < 16; nf++) rsum[nf] = 0.f;

    if (ce > 0) {
        const int F = (ce + 15) >> 4;
        for (int f = 0; f < F; f++) {
            int p = f * 16 + (lane & 15);
            p = p < ce ? p : ce - 1;
            const float* P0 = Pb + (size_t)Lj[p] * NH;

            f32x4_t acc[16];
            const f32x4_t z4 = {0.f, 0.f, 0.f, 0.f};
#pragma unroll
            for (int nf = 0; nf < 16; nf++) acc[nf] = z4;

#pragma unroll 2
            for (int kk = 0; kk < 8; kk++) {
                const int ko = kk * 32 + (lane >> 4) * 8;
                const float4 q0 = *(const float4*)(Qj + ko);
                const float4 q1 = *(const float4*)(Qj + ko + 4);
                const float4 p0 = *(const float4*)(P0 + ko);
                const float4 p1 = *(const float4*)(P0 + ko + 4);
                const bf16x8_t af = a_genf(p0, p1, q0, q1);
#pragma unroll
                for (int nf = 0; nf < 16; nf++) {
                    const bf16x8_t bfr = *(const bf16x8_t*)(&Bl[(nf * 8 + kk) * 512 + lane * 8]);
                    acc[nf] = __builtin_amdgcn_mfma_f32_16x16x32_bf16(af, bfr, acc[nf], 0, 0, 0);
                }
            }
            // epilogue: bias+relu+row-mask, cross-lane col reduce
#pragma unroll
            for (int nf = 0; nf < 16; nf++) {
                float s = 0.f;
#pragma unroll
                for (int r = 0; r < 4; r++) {
                    const int pos = f * 16 + ((lane >> 4) << 2) + r;
                    if (pos < ce) s += fmaxf(acc[nf][r] + bb[nf], 0.f);
                }
                s += __shfl_xor(s, 16, 64);
                s += __shfl_xor(s, 32, 64);
                if (lane < 16) rsum[nf] += s;
            }
        }
    }
    // direct store (unique writer per (b,e,j,col); ce==0 writes zeros)
    if (lane < 16) {
        float* dst = aggr3 + (size_t)((b * NE + e) * NN + j) * NH + lane;
#pragma unroll
        for (int nf = 0; nf < 16; nf++) dst[nf * 16] = rsum[nf];
    }
}

// ============ Kernel 3: decoder, 8 j's per block (weight reuse x8) ============
__global__ __launch_bounds__(256) void dec_kernel(
    const float* __restrict__ ns,
    const float* __restrict__ aggr3,
    const float* __restrict__ Wd1, const float* __restrict__ bd1,
    const float* __restrict__ Wd2, const float* __restrict__ bd2,
    float* __restrict__ out)
{
    const int b = blockIdx.x >> 4;
    const int jg = blockIdx.x & 15;
    const int tid = threadIdx.x;
    __shared__ __align__(16) float xs[8][320];
    __shared__ __align__(16) float o1s[8][NH];

    // stage x = [ns(64) | sum_e aggr3(256)] for 8 j's
    for (int x = tid; x < 8 * 320; x += 256) {
        const int jj = x / 320, k = x % 320;
        const int j = jg * 8 + jj;
        float v;
        if (k < ND) v = ns[(size_t)(b * NN + j) * ND + k];
        else {
            const int c = k - ND;
            v = aggr3[(size_t)((b * NE + 0) * NN + j) * NH + c]
              + aggr3[(size_t)((b * NE + 1) * NN + j) * NH + c]
              + aggr3[(size_t)((b * NE + 2) * NN + j) * NH + c];
        }
        xs[jj][k] = v;
    }
    __syncthreads();
    // layer 1: thread owns col n; 8 j's share each weight load
    {
        const int n = tid;
        float acc[8];
        const float b1 = bd1[n];
#pragma unroll
        for (int jj = 0; jj < 8; jj++) acc[jj] = b1;
        for (int k4 = 0; k4 < 80; k4++) {
            const float w0 = Wd1[(size_t)(k4 * 4 + 0) * NH + n];
            const float w1 = Wd1[(size_t)(k4 * 4 + 1) * NH + n];
            const float w2 = Wd1[(size_t)(k4 * 4 + 2) * NH + n];
            const float w3 = Wd1[(size_t)(k4 * 4 + 3) * NH + n];
#pragma unroll
            for (int jj = 0; jj < 8; jj++) {
                const float4 xv = *(const float4*)(&xs[jj][k4 * 4]);
                acc[jj] = fmaf(xv.x, w0, fmaf(xv.y, w1, fmaf(xv.z, w2, fmaf(xv.w, w3, acc[jj]))));
            }
        }
#pragma unroll
        for (int jj = 0; jj < 8; jj++) o1s[jj][n] = fmaxf(acc[jj], 0.f);
    }
    __syncthreads();
    // layer 2: thread = (jj, 2 cols)
    {
        const int jj = tid >> 5, cp = tid & 31;
        const int n0 = cp * 2;
        float a0 = bd2[n0], a1 = bd2[n0 + 1];
        for (int h4 = 0; h4 < 64; h4++) {
            const float4 ov = *(const float4*)(&o1s[jj][h4 * 4]);
            a0 = fmaf(ov.x, Wd2[(size_t)(h4 * 4 + 0) * NOUT + n0], a0);
            a1 = fmaf(ov.x, Wd2[(size_t)(h4 * 4 + 0) * NOUT + n0 + 1], a1);
            a0 = fmaf(ov.y, Wd2[(size_t)(h4 * 4 + 1) * NOUT + n0], a0);
            a1 = fmaf(ov.y, Wd2[(size_t)(h4 * 4 + 1) * NOUT + n0 + 1], a1);
            a0 = fmaf(ov.z, Wd2[(size_t)(h4 * 4 + 2) * NOUT + n0], a0);
            a1 = fmaf(ov.z, Wd2[(size_t)(h4 * 4 + 2) * NOUT + n0 + 1], a1);
            a0 = fmaf(ov.w, Wd2[(size_t)(h4 * 4 + 3) * NOUT + n0], a0);
            a1 = fmaf(ov.w, Wd2[(size_t)(h4 * 4 + 3) * NOUT + n0 + 1], a1);
        }
        const int j = jg * 8 + jj;
        out[(size_t)(b * NN + j) * NOUT + n0] = fmaxf(a0, 0.f);
        out[(size_t)(b * NN + j) * NOUT + n0 + 1] = fmaxf(a1, 0.f);
    }
}

extern "C" void kernel_launch(void* const* d_in, const int* in_sizes, int n_in,
                              void* d_out, int out_size, void* d_ws, size_t ws_size,
                              hipStream_t stream)
{
    const float* ns    = (const float*)d_in[0];
    const float* edges = (const float*)d_in[1];
    const float* We1   = (const float*)d_in[2];
    const float* be1   = (const float*)d_in[3];
    const float* We2   = (const float*)d_in[4];
    const float* be2   = (const float*)d_in[5];
    const float* Wd1   = (const float*)d_in[6];
    const float* bd1   = (const float*)d_in[7];
    const float* Wd2   = (const float*)d_in[8];
    const float* bd2   = (const float*)d_in[9];
    float* outp = (float*)d_out;

    // ws layout (~10.2 MB)
    float* Pf = (float*)d_ws;                               // 786432 f32
    float* Qf = Pf + (size_t)NB * NE * NN * NH;             // 786432 f32
    ushort_t* We2p = (ushort_t*)(Qf + (size_t)NB * NE * NN * NH); // 196608 us
    ushort_t* list_ws = We2p + (size_t)NE * NH * NH;        // 131072 us
    int4* cnts_ws = (int4*)(list_ws + (size_t)NB * NN * NN);// 1024 int4
    float* aggr3 = (float*)(cnts_ws + NB * NN);             // 786432 f32

    hipLaunchKernelGGL(prep_kernel, dim3(1264), dim3(256), 0, stream,
                       We2, ns, We1, be1, edges, We2p, Pf, Qf, list_ws, cnts_ws);
    hipLaunchKernelGGL(gemm_kernel, dim3(384), dim3(512), 0, stream,
                       Pf, Qf, We2p, be2, list_ws, cnts_ws, aggr3);
    hipLaunchKernelGGL(dec_kernel, dim3(NB * 16), dim3(256), 0, stream,
                       ns, aggr3, Wd1, bd1, Wd2, bd2, outp);
}